// Round 4
// baseline (399.957 us; speedup 1.0000x reference)
//
#include <hip/hip_runtime.h>
#include <hip/hip_bf16.h>

typedef unsigned short u16;
typedef unsigned int u32;
typedef __bf16 bf16x8 __attribute__((ext_vector_type(8)));
typedef float f32x4 __attribute__((ext_vector_type(4)));
typedef unsigned int u32x4 __attribute__((ext_vector_type(4)));

// ---------------- constants ----------------
#define BATCH 8
#define SEQ   2048
#define DIM   1024
#define M_TOT (BATCH * SEQ)      // 16384
#define N_QKV (3 * DIM)          // 3072

// workspace layout (bytes) — peak 201,326,592 (192 MiB)
//   [0, 100663296)            qkv bf16 (16384 x 3072)
//   [100663296, 134217728)    vt  bf16 (8 x 1024 x 2048)
//   [134217728, ...)          region C, time-multiplexed:
//       phase 1: xb bf16 (33,554,432) + wt bf16 (6,291,456)   [dead after QKV GEMM]
//       phase 2: S/P bf16 (8 x 2048 x 2048 x 2 = 67,108,864)  [softmax in-place]
#define OFF_QKV  ((size_t)0)
#define OFF_VT   ((size_t)100663296)
#define OFF_C    ((size_t)134217728)
#define OFF_XB   OFF_C
#define OFF_WT   (OFF_C + (size_t)33554432)
#define OFF_S    OFF_C

__device__ __forceinline__ u16 f32_to_bf16(float f) {
    u32 u = __builtin_bit_cast(u32, f);
    u = (u + 0x7fffu + ((u >> 16) & 1u)) >> 16;
    return (u16)u;
}

__device__ __forceinline__ float bf16_to_f32(u16 h) {
    u32 u = ((u32)h) << 16;
    return __builtin_bit_cast(float, u);
}

__device__ __forceinline__ bf16x8 lds_load8(const u16* p) {
    return __builtin_bit_cast(bf16x8, *(const u32x4*)p);
}

// ================= 256x256 / BK=64 deep-pipelined GEMM core =================
// 512 threads = 8 waves (2 M x 4 N), per-wave 128x64 output = acc[8][4] of
// 16x16x32 bf16 MFMA fragments.
//
// LDS = 8 units of 16 KiB (256 rows x 32 bf16): units 0..3 = A, 4..7 = B.
// Unit for K-tile t, K-half ks lives in slot (t&1)*2 + ks  (double buffer).
//
// Swizzle (round-3, verified conflict-free: SQ_LDS_BANK_CONFLICT == 0):
//   slot(row,kg) = (row>>3)*32 + 8*((row>>1)&3) + ((row + 2*kg) & 7)
// Fragment reads hit bank-quad (lrow + 2*kgl)&7 — distinct across each
// 8-lane group.  global_load_lds writes linearly; the *global source*
// applies the inverse permutation.
//
// Phase shape (round-4 fix, = m201 template): ds_reads for THIS phase are
// issued BEFORE the barrier, so their ~200cyc latency drains during barrier
// convergence / other waves' MFMA; after the barrier a single lgkmcnt(0)
// is nearly free and the MFMA cluster runs back-to-back.  Round-3's shape
// (barrier -> ds_read -> wait -> MFMA) exposed the full LDS round-trip
// serially in every phase (MfmaUtil stuck at 38% with zero conflicts).
#define UNIT 8192  // u16 elements per 16 KiB unit

__device__ __forceinline__ void stage_unit(const u16* g, size_t lda, int k0,
                                           u16* lds, int tid) {
    int wv = tid >> 6;
#pragma unroll
    for (int iss = 0; iss < 2; ++iss) {
        int s = iss * 512 + tid;            // linear chunk slot 0..1023
        // invert slot -> (row, kg)
        int o = s & 31;
        int p = o >> 3;                     // (row>>1)&3
        int q = o & 7;                      // (row + 2*kg)&7
        int row = ((s >> 5) << 3) + (p << 1) + (q & 1);
        int kg = ((q - (p << 1) - (q & 1)) & 7) >> 1;
        const u16* gp = g + (size_t)row * lda + (k0 + (kg << 3));
        u16* lp = lds + (size_t)(iss * 512 + wv * 64) * 8;  // wave-uniform base
        __builtin_amdgcn_global_load_lds((const __attribute__((address_space(1))) void*)gp,
                                         (__attribute__((address_space(3))) void*)lp,
                                         16, 0, 0);
    }
}

// Issue 8 ds_read_b128 for one phase's fragments (M-half MH x one K-half).
template <int MH>
__device__ __forceinline__ void ds_load_frags(const u16* uA, const u16* uB, int lane,
                                              int wm, int wn, bf16x8 a[4], bf16x8 b[4]) {
    int lrow = lane & 15;
    int kgl = lane >> 4;
    int rb = lrow >> 3;
    int base_l = ((lrow >> 1) & 3) * 64 + ((lrow + 2 * kgl) & 7) * 8;
#pragma unroll
    for (int i = 0; i < 4; ++i) {
        a[i] = lds_load8(&uA[(size_t)((wm * 16 + (MH * 4 + i) * 2 + rb) * 256 + base_l)]);
        b[i] = lds_load8(&uB[(size_t)((wn * 8 + i * 2 + rb) * 256 + base_l)]);
    }
}

template <int MH>
__device__ __forceinline__ void mfma_compute(const bf16x8 a[4], const bf16x8 b[4],
                                             f32x4 acc[8][4]) {
    __builtin_amdgcn_s_setprio(1);
#pragma unroll
    for (int i = 0; i < 4; ++i)
#pragma unroll
        for (int j = 0; j < 4; ++j)
            acc[MH * 4 + i][j] =
                __builtin_amdgcn_mfma_f32_16x16x32_bf16(a[i], b[j], acc[MH * 4 + i][j], 0, 0, 0);
    __builtin_amdgcn_s_setprio(0);
}

// Pipelined main loop.  Per tile t (4 phases), steady-state per-wave vmcnt
// ledger (2 loads per stage_unit):
//   enter t: 4 outstanding [A(t,1),B(t,1)]
//   P0: ds_read (t,0); stage A(t+1,0) -> 6;            barrier; MFMA MH0xK0
//   P1: ds_read (t,0); stage B(t+1,0) -> 8; vmcnt(4)   [retires A(t,1),B(t,1)]
//       barrier; MFMA MH1xK0
//   P2: ds_read (t,1); stage A(t+1,1) -> 6;            barrier; MFMA MH0xK1
//   P3: ds_read (t,1); stage B(t+1,1) -> 8; vmcnt(4)   [retires A(t+1,0),B(t+1,0)]
//       barrier; MFMA MH1xK1
// Every ds_read touches a unit vmcnt-retired >=1 barrier earlier; every
// stage overwrites a unit whose last reader finished >=2 barriers earlier.
// Last tile: no stages; P1 waits vmcnt(0).  All branches wave-uniform.
__device__ __forceinline__ void gemm_block_256(const u16* __restrict__ A, size_t lda,
                                               const u16* __restrict__ B, size_t ldb,
                                               int KT, u16* lds, int tid,
                                               f32x4 acc[8][4]) {
    int lane = tid & 63;
    int wv = tid >> 6;
    int wm = wv >> 2, wn = wv & 3;
    // prologue: tile 0's 4 units; retire half 0 before first reads
    stage_unit(A, lda, 0,  lds + 0 * UNIT, tid);   // A(0,0)
    stage_unit(B, ldb, 0,  lds + 4 * UNIT, tid);   // B(0,0)
    stage_unit(A, lda, 32, lds + 1 * UNIT, tid);   // A(0,1)
    stage_unit(B, ldb, 32, lds + 5 * UNIT, tid);   // B(0,1)
    asm volatile("s_waitcnt vmcnt(4)" ::: "memory");
    __builtin_amdgcn_s_barrier();
    for (int t = 0; t < KT; ++t) {
        int p = t & 1, pn = p ^ 1;
        int kb = (t + 1) << 6;
        bool pf = (t + 1 < KT);
        const u16* uA0 = lds + (size_t)(p * 2) * UNIT;
        const u16* uB0 = lds + (size_t)(4 + p * 2) * UNIT;
        const u16* uA1 = lds + (size_t)(p * 2 + 1) * UNIT;
        const u16* uB1 = lds + (size_t)(4 + p * 2 + 1) * UNIT;
        bf16x8 a[4], b[4];
        // ---- P0 ----
        ds_load_frags<0>(uA0, uB0, lane, wm, wn, a, b);
        if (pf) stage_unit(A, lda, kb, lds + (size_t)(pn * 2) * UNIT, tid);
        __builtin_amdgcn_s_barrier();
        asm volatile("s_waitcnt lgkmcnt(0)" ::: "memory");
        mfma_compute<0>(a, b, acc);
        __builtin_amdgcn_s_barrier();
        // ---- P1 ----
        ds_load_frags<1>(uA0, uB0, lane, wm, wn, a, b);
        if (pf) {
            stage_unit(B, ldb, kb, lds + (size_t)(4 + pn * 2) * UNIT, tid);
            asm volatile("s_waitcnt vmcnt(4)" ::: "memory");
        } else {
            asm volatile("s_waitcnt vmcnt(0)" ::: "memory");
        }
        __builtin_amdgcn_s_barrier();
        asm volatile("s_waitcnt lgkmcnt(0)" ::: "memory");
        mfma_compute<1>(a, b, acc);
        __builtin_amdgcn_s_barrier();
        // ---- P2 ----
        ds_load_frags<0>(uA1, uB1, lane, wm, wn, a, b);
        if (pf) stage_unit(A, lda, kb + 32, lds + (size_t)(pn * 2 + 1) * UNIT, tid);
        __builtin_amdgcn_s_barrier();
        asm volatile("s_waitcnt lgkmcnt(0)" ::: "memory");
        mfma_compute<0>(a, b, acc);
        __builtin_amdgcn_s_barrier();
        // ---- P3 ----
        ds_load_frags<1>(uA1, uB1, lane, wm, wn, a, b);
        if (pf) {
            stage_unit(B, ldb, kb + 32, lds + (size_t)(4 + pn * 2 + 1) * UNIT, tid);
            asm volatile("s_waitcnt vmcnt(4)" ::: "memory");
        }
        __builtin_amdgcn_s_barrier();
        asm volatile("s_waitcnt lgkmcnt(0)" ::: "memory");
        mfma_compute<1>(a, b, acc);
        __builtin_amdgcn_s_barrier();
    }
}

// ---------------- kernel 1: cast x fp32 -> bf16 ----------------
__global__ __launch_bounds__(256) void cast_x_kernel(const float* __restrict__ x,
                                                     u16* __restrict__ xb) {
    size_t g = (size_t)blockIdx.x * 256 + threadIdx.x;   // group of 4 elems
    f32x4 v = ((const f32x4*)x)[g];
    u16 o[4] = {f32_to_bf16(v.x), f32_to_bf16(v.y), f32_to_bf16(v.z), f32_to_bf16(v.w)};
    *(unsigned long long*)(xb + g * 4) = *(const unsigned long long*)o;
}

// ---------------- kernel 2: transpose-cast W [k][n] fp32 -> Wt [n][k] bf16 ----------------
__global__ __launch_bounds__(256) void transpose_w_kernel(const float* __restrict__ wq,
                                                          const float* __restrict__ wk,
                                                          const float* __restrict__ wv,
                                                          u16* __restrict__ wt) {
    __shared__ __align__(16) u16 tile[64][80];
    const float* w = blockIdx.z == 0 ? wq : (blockIdx.z == 1 ? wk : wv);
    int k0 = blockIdx.x * 64, n0 = blockIdx.y * 64;
    for (int g = threadIdx.x; g < 1024; g += 256) {
        int r = g >> 4, c = (g & 15) << 2;
        f32x4 v = *(const f32x4*)(w + (size_t)(k0 + r) * 1024 + n0 + c);
        tile[r][c + 0] = f32_to_bf16(v.x);
        tile[r][c + 1] = f32_to_bf16(v.y);
        tile[r][c + 2] = f32_to_bf16(v.z);
        tile[r][c + 3] = f32_to_bf16(v.w);
    }
    __syncthreads();
    u16* out = wt + (size_t)blockIdx.z * 1024 * 1024;
    for (int g = threadIdx.x; g < 512; g += 256) {
        int nr = g >> 3, kc = (g & 7) << 3;
        __align__(16) u16 tmp[8];
#pragma unroll
        for (int i = 0; i < 8; ++i) tmp[i] = tile[kc + i][nr];
        *(u32x4*)(out + (size_t)(n0 + nr) * 1024 + k0 + kc) = *(const u32x4*)tmp;
    }
}

// ---------------- kernel 3: QKV GEMM (256^2 pipelined): qkv[m][n'] = xb[m][:] . wt[n'][:] ----
__global__ __launch_bounds__(512, 2) void gemm_qkv_kernel(const u16* __restrict__ xb,
                                                          const u16* __restrict__ wt,
                                                          u16* __restrict__ qkv) {
    __shared__ __align__(16) u16 lds[8 * UNIT];
    // XCD-aware swizzle (T1): 768 % 8 == 0, simple variant is bijective
    int wg = blockIdx.x;
    int qx = gridDim.x >> 3;
    int swz = (wg & 7) * qx + (wg >> 3);
    int mt = swz / 12, nt = swz - mt * 12;   // nt fastest: A-panel L2 reuse per XCD
    const u16* A = xb + (size_t)mt * 256 * 1024;
    const u16* B = wt + (size_t)nt * 256 * 1024;
    int tid = threadIdx.x;
    f32x4 acc[8][4] = {};
    gemm_block_256(A, 1024, B, 1024, 16, lds, tid, acc);
    int lane = tid & 63, wv = tid >> 6;
    int wm = wv >> 2, wn = wv & 3;
    int r0 = (lane >> 4) << 2, c0 = lane & 15;
    size_t mbase = (size_t)mt * 256 + wm * 128;
    int nbase = nt * 256 + wn * 64;
#pragma unroll
    for (int i = 0; i < 8; ++i)
#pragma unroll
        for (int j = 0; j < 4; ++j) {
            int col = nbase + j * 16 + c0;
            float scale = (col < 1024) ? 0.03125f : 1.0f;  // fold 1/sqrt(1024) into Q
#pragma unroll
            for (int r = 0; r < 4; ++r) {
                size_t row = mbase + i * 16 + r0 + r;
                qkv[row * (size_t)N_QKV + col] = f32_to_bf16(acc[i][j][r] * scale);
            }
        }
}

// ---------------- kernel 4: transpose V -> Vt [b][d][m] ----------------
__global__ __launch_bounds__(256) void transpose_v_kernel(const u16* __restrict__ qkv,
                                                          u16* __restrict__ vt) {
    __shared__ __align__(16) u16 tile[64][80];
    int m0 = blockIdx.x * 64, d0 = blockIdx.y * 64, b = blockIdx.z;
    const u16* src = qkv + (size_t)b * SEQ * N_QKV + 2048;  // V columns
    for (int g = threadIdx.x; g < 512; g += 256) {
        int r = g >> 3, c = (g & 7) << 3;
        *(u32x4*)&tile[r][c] = *(const u32x4*)(src + (size_t)(m0 + r) * N_QKV + d0 + c);
    }
    __syncthreads();
    u16* dst = vt + (size_t)b * DIM * SEQ;
    for (int g = threadIdx.x; g < 512; g += 256) {
        int dr = g >> 3, mc = (g & 7) << 3;
        __align__(16) u16 tmp[8];
#pragma unroll
        for (int i = 0; i < 8; ++i) tmp[i] = tile[mc + i][dr];
        *(u32x4*)(dst + (size_t)(d0 + dr) * SEQ + m0 + mc) = *(const u32x4*)tmp;
    }
}

// ---------------- kernel 5: S = Q . K^T, triangular 256-tile grid, bf16 out ----------------
__global__ __launch_bounds__(512, 2) void gemm_scores_kernel(const u16* __restrict__ qkv,
                                                             u16* __restrict__ S) {
    __shared__ __align__(16) u16 lds[8 * UNIT];
    int t = blockIdx.x;      // 0..35 triangular index over 8x8 256-tiles
    int b = blockIdx.y;
    // bounded integer triangular decomposition (no FP, <= 7 iterations)
    int ntile = 0;
#pragma unroll
    for (int it = 1; it < 8; ++it)
        if ((it * (it + 1)) / 2 <= t) ntile = it;
    int mtile = t - (ntile * (ntile + 1)) / 2;   // 0 <= mtile <= ntile
    const u16* A = qkv + (size_t)b * SEQ * N_QKV + (size_t)ntile * 256 * N_QKV;        // Q rows
    const u16* B = qkv + (size_t)b * SEQ * N_QKV + (size_t)mtile * 256 * N_QKV + 1024; // K rows
    int tid = threadIdx.x;
    f32x4 acc[8][4] = {};
    gemm_block_256(A, N_QKV, B, N_QKV, 16, lds, tid, acc);
    u16* out = S + (size_t)b * SEQ * SEQ + (size_t)ntile * 256 * SEQ + (size_t)mtile * 256;
    int lane = tid & 63, wv = tid >> 6;
    int wm = wv >> 2, wn = wv & 3;
    int r0 = (lane >> 4) << 2, c0 = lane & 15;
#pragma unroll
    for (int i = 0; i < 8; ++i)
#pragma unroll
        for (int j = 0; j < 4; ++j) {
            int col = wn * 64 + j * 16 + c0;
#pragma unroll
            for (int r = 0; r < 4; ++r) {
                int row = wm * 128 + i * 16 + r0 + r;
                out[(size_t)row * SEQ + col] = f32_to_bf16(acc[i][j][r]);
            }
        }
}

// ---------------- kernel 6: row softmax over bf16 S, in-place, register-resident ----
__global__ __launch_bounds__(256) void softmax_kernel(u16* __restrict__ SP) {
    int gr = blockIdx.x;
    int n = gr & 2047;
    u16* s = SP + (size_t)gr * SEQ;
    __shared__ float red[4];
    int t = threadIdx.x;
    int base = t << 3;
    int len = n + 1;
    float v[8];
    float lmax = -3.0e38f;
    if (base < len) {
        u32x4 raw = *(const u32x4*)(s + base);
        const u16* h = (const u16*)&raw;
#pragma unroll
        for (int i = 0; i < 8; ++i) {
            v[i] = (base + i < len) ? bf16_to_f32(h[i]) : -3.0e38f;
            lmax = fmaxf(lmax, v[i]);
        }
    } else {
#pragma unroll
        for (int i = 0; i < 8; ++i) v[i] = -3.0e38f;
    }
#pragma unroll
    for (int off = 32; off; off >>= 1) lmax = fmaxf(lmax, __shfl_xor(lmax, off, 64));
    if ((t & 63) == 0) red[t >> 6] = lmax;
    __syncthreads();
    float gmax = fmaxf(fmaxf(red[0], red[1]), fmaxf(red[2], red[3]));
    __syncthreads();   // everyone has gmax before red is reused
    float lsum = 0.f;
#pragma unroll
    for (int i = 0; i < 8; ++i) {
        float e = __expf(v[i] - gmax);   // masked lanes -> exp(-huge) = 0
        v[i] = e;
        lsum += e;
    }
#pragma unroll
    for (int off = 32; off; off >>= 1) lsum += __shfl_xor(lsum, off, 64);
    if ((t & 63) == 0) red[t >> 6] = lsum;
    __syncthreads();
    float inv = 1.0f / (red[0] + red[1] + red[2] + red[3]);
    __align__(16) u16 o[8];
#pragma unroll
    for (int i = 0; i < 8; ++i) o[i] = f32_to_bf16(v[i] * inv);  // masked lanes write 0
    *(u32x4*)(s + base) = *(const u32x4*)o;
}

// ---------------- kernel 7: O = P . V (via Vt), causal K truncation, 256^2 ----------------
// ntile reversed so the longest blocks (KT=32) dispatch first (tail balance).
__global__ __launch_bounds__(512, 2) void gemm_out_kernel(const u16* __restrict__ P,
                                                          const u16* __restrict__ vt,
                                                          float* __restrict__ O) {
    __shared__ __align__(16) u16 lds[8 * UNIT];
    int dt = blockIdx.x, b = blockIdx.z;
    int ntile = (SEQ / 256 - 1) - blockIdx.y;
    const u16* A = P + (size_t)b * SEQ * SEQ + (size_t)ntile * 256 * SEQ;
    const u16* B = vt + (size_t)b * DIM * SEQ + (size_t)dt * 256 * SEQ;
    int tid = threadIdx.x;
    f32x4 acc[8][4] = {};
    int KT = (ntile + 1) * 4;  // keys beyond (ntile+1)*256 have P == 0
    gemm_block_256(A, SEQ, B, SEQ, KT, lds, tid, acc);
    float* out = O + (size_t)b * SEQ * DIM + (size_t)ntile * 256 * DIM + (size_t)dt * 256;
    int lane = tid & 63, wv = tid >> 6;
    int wm = wv >> 2, wn = wv & 3;
    int r0 = (lane >> 4) << 2, c0 = lane & 15;
#pragma unroll
    for (int i = 0; i < 8; ++i)
#pragma unroll
        for (int j = 0; j < 4; ++j) {
            int col = wn * 64 + j * 16 + c0;
#pragma unroll
            for (int r = 0; r < 4; ++r) {
                int row = wm * 128 + i * 16 + r0 + r;
                out[(size_t)row * DIM + col] = acc[i][j][r];
            }
        }
}

extern "C" void kernel_launch(void* const* d_in, const int* in_sizes, int n_in,
                              void* d_out, int out_size, void* d_ws, size_t ws_size,
                              hipStream_t stream) {
    const float* x = (const float*)d_in[0];
    const float* wq = (const float*)d_in[1];
    const float* wk = (const float*)d_in[2];
    const float* wv = (const float*)d_in[3];
    char* ws = (char*)d_ws;
    u16* qkv = (u16*)(ws + OFF_QKV);
    u16* vt = (u16*)(ws + OFF_VT);
    u16* xb = (u16*)(ws + OFF_XB);
    u16* wt = (u16*)(ws + OFF_WT);
    u16* S = (u16*)(ws + OFF_S);   // aliases xb/wt region (dead by then)
    float* O = (float*)d_out;

    cast_x_kernel<<<M_TOT * DIM / 4 / 256, 256, 0, stream>>>(x, xb);
    transpose_w_kernel<<<dim3(16, 16, 3), 256, 0, stream>>>(wq, wk, wv, wt);
    gemm_qkv_kernel<<<(M_TOT / 256) * (N_QKV / 256), 512, 0, stream>>>(xb, wt, qkv);
    transpose_v_kernel<<<dim3(SEQ / 64, DIM / 64, BATCH), 256, 0, stream>>>(qkv, vt);
    gemm_scores_kernel<<<dim3(36, BATCH), 512, 0, stream>>>(qkv, S);
    softmax_kernel<<<BATCH * SEQ, 256, 0, stream>>>(S);
    gemm_out_kernel<<<dim3(DIM / 256, SEQ / 256, BATCH), 512, 0, stream>>>(S, vt, O);
}

// Round 5
// 393.276 us; speedup vs baseline: 1.0170x; 1.0170x over previous
//
#include <hip/hip_runtime.h>
#include <hip/hip_bf16.h>

typedef unsigned short u16;
typedef unsigned int u32;
typedef __bf16 bf16x8 __attribute__((ext_vector_type(8)));
typedef float f32x4 __attribute__((ext_vector_type(4)));
typedef unsigned int u32x4 __attribute__((ext_vector_type(4)));

// ---------------- constants ----------------
#define BATCH 8
#define SEQ   2048
#define DIM   1024
#define M_TOT (BATCH * SEQ)      // 16384
#define N_QKV (3 * DIM)          // 3072

// workspace layout (bytes) — peak 201,326,592 (192 MiB)
#define OFF_QKV  ((size_t)0)
#define OFF_VT   ((size_t)100663296)
#define OFF_C    ((size_t)134217728)
#define OFF_XB   OFF_C
#define OFF_WT   (OFF_C + (size_t)33554432)
#define OFF_S    OFF_C

__device__ __forceinline__ u16 f32_to_bf16(float f) {
    u32 u = __builtin_bit_cast(u32, f);
    u = (u + 0x7fffu + ((u >> 16) & 1u)) >> 16;
    return (u16)u;
}

__device__ __forceinline__ float bf16_to_f32(u16 h) {
    u32 u = ((u32)h) << 16;
    return __builtin_bit_cast(float, u);
}

__device__ __forceinline__ bf16x8 lds_load8(const u16* p) {
    return __builtin_bit_cast(bf16x8, *(const u32x4*)p);
}

// ============ 256x256 / BK=32 / 5-tile-ring deep-pipelined GEMM core ============
// 512 threads = 8 waves (2M x 4N), per-wave 128x64 output = acc[8][4].
// Per K-tile (K=32): 2 phases (M-halves), 16 MFMA each; B-fragments read once
// per tile (P0) and reused in registers at P1 (12 b128/tile/wave total).
//
// LDS = 40 quarter-units of 4 KiB (64 rows x 32 cols bf16): 20 A + 20 B =
// 5-tile ring (160 KiB, whole CU).  A(t,q)/B(t,q) at slot (t%5)*4+q.
// Tile t+4 is staged during tile t -> loads live ~8 phases; steady-state
// wait is vmcnt(12) (16 in flight, 4 retired) ONCE per tile — never 0.
//
// Swizzle: row = 64 B = 4 chunks; chunk (row,c) stored at slot c ^ ((row>>1)&3).
// bank-quad = 4*(row&1) + (c ^ ((row>>1)&3)) -> distinct across every 8 lanes
// on both the ds_read side and the linear staging-write side.  The global
// source applies the same XOR (involution), so staged chunks of one row are a
// permutation WITHIN the same 64 B segment (coalesced).
#define U4 2048   // u16 elems per 4 KiB quarter-unit
#define NSLOT 20  // quarter-units per operand (5 tiles x 4)

// Stage one 8-KiB pair of quarter-units (qbase, qbase+1) of a tile column k0.
// 512 threads x 1 load x 16 B.  Waves 0-3 -> quarter qbase, 4-7 -> qbase+1.
__device__ __forceinline__ void stage_pair(const u16* g, size_t lda, int k0,
                                           int qbase, u16* lpair, int tid) {
    int wv = tid >> 6;
    int lane = tid & 63;
    int u = wv >> 2;                    // which quarter of the pair
    int su = ((wv & 3) << 6) + lane;    // chunk 0..255 within quarter
    int row = su >> 2, sc = su & 3;
    int c = sc ^ ((row >> 1) & 3);      // inverse-swizzled global chunk
    const u16* gp = g + (size_t)((qbase + u) * 64 + row) * lda + k0 + (c << 3);
    u16* lp = lpair + u * U4 + ((wv & 3) << 9);   // wave-uniform base
    __builtin_amdgcn_global_load_lds((const __attribute__((address_space(1))) void*)gp,
                                     (__attribute__((address_space(3))) void*)lp,
                                     16, 0, 0);
}

// 4 A-fragment reads (+ optionally 4 B) for one phase.
template <bool LOADB>
__device__ __forceinline__ void frags_read(const u16* uA, const u16* uB, int lane,
                                           bf16x8 a[4], bf16x8 b[4]) {
    int lrow = lane & 15, kgl = lane >> 4;
    int sl = (kgl ^ ((lrow >> 1) & 3)) << 3;   // swizzled chunk offset (elems)
#pragma unroll
    for (int i = 0; i < 4; ++i) {
        a[i] = lds_load8(&uA[(i * 16 + lrow) * 32 + sl]);
        if (LOADB) b[i] = lds_load8(&uB[(i * 16 + lrow) * 32 + sl]);
    }
}

template <int MH>
__device__ __forceinline__ void mfma16(const bf16x8 a[4], const bf16x8 b[4],
                                       f32x4 acc[8][4]) {
    __builtin_amdgcn_s_setprio(1);
#pragma unroll
    for (int i = 0; i < 4; ++i)
#pragma unroll
        for (int j = 0; j < 4; ++j)
            acc[MH * 4 + i][j] =
                __builtin_amdgcn_mfma_f32_16x16x32_bf16(a[i], b[j], acc[MH * 4 + i][j], 0, 0, 0);
    __builtin_amdgcn_s_setprio(0);
}

// Per tile t:
//  P0: read A(t,wm*2+0) + B(t,wn); stage A(t+4) pairs; bar; lgkm0; MFMA; bar
//  P1: read A(t,wm*2+1) (reuse B); stage B(t+4) pairs; vmcnt(12); bar; lgkm0; MFMA; bar
// WAR: slot(t+4) == slot(t-1), whose last read completed >=1 barrier before the
// stage issue.  RAW: vmcnt(12) at t P1 retires exactly tile t+1's 4 loads
// (issue order is strictly tile-ordered), 2 barriers before t+1 P0's reads.
// Tail: waits step 12->8->4->0 as staging ceases.  KT >= 4 required.
__device__ __forceinline__ void gemm_block_256(const u16* __restrict__ A, size_t lda,
                                               const u16* __restrict__ B, size_t ldb,
                                               int KT, u16* ldsA, u16* ldsB, int tid,
                                               f32x4 acc[8][4]) {
    int lane = tid & 63;
    int wv = tid >> 6;
    int wm = wv >> 2, wn = wv & 3;
    // prologue: stage tiles 0..3, retire tile 0
#pragma unroll
    for (int pt = 0; pt < 4; ++pt) {
        stage_pair(A, lda, pt << 5, 0, ldsA + (pt * 4 + 0) * U4, tid);
        stage_pair(A, lda, pt << 5, 2, ldsA + (pt * 4 + 2) * U4, tid);
        stage_pair(B, ldb, pt << 5, 0, ldsB + (pt * 4 + 0) * U4, tid);
        stage_pair(B, ldb, pt << 5, 2, ldsB + (pt * 4 + 2) * U4, tid);
    }
    asm volatile("s_waitcnt vmcnt(12)" ::: "memory");
    __builtin_amdgcn_s_barrier();
    int rt = 0, rs = 4;
    for (int t = 0; t < KT; ++t) {
        const u16* uA0 = ldsA + (rt * 4 + wm * 2) * U4;
        const u16* uA1 = uA0 + U4;
        const u16* uB  = ldsB + (rt * 4 + wn) * U4;
        bool pf = (t + 4 < KT);
        int k4 = (t + 4) << 5;
        bf16x8 a[4], b[4];
        // ---- P0 ----
        frags_read<true>(uA0, uB, lane, a, b);
        if (pf) {
            stage_pair(A, lda, k4, 0, ldsA + (rs * 4 + 0) * U4, tid);
            stage_pair(A, lda, k4, 2, ldsA + (rs * 4 + 2) * U4, tid);
        }
        __builtin_amdgcn_s_barrier();
        asm volatile("s_waitcnt lgkmcnt(0)" ::: "memory");
        mfma16<0>(a, b, acc);
        __builtin_amdgcn_s_barrier();
        // ---- P1 ----
        frags_read<false>(uA1, uB, lane, a, b);   // B reused from P0
        if (pf) {
            stage_pair(B, ldb, k4, 0, ldsB + (rs * 4 + 0) * U4, tid);
            stage_pair(B, ldb, k4, 2, ldsB + (rs * 4 + 2) * U4, tid);
            asm volatile("s_waitcnt vmcnt(12)" ::: "memory");
        } else if (t + 3 < KT) {
            asm volatile("s_waitcnt vmcnt(8)" ::: "memory");
        } else if (t + 2 < KT) {
            asm volatile("s_waitcnt vmcnt(4)" ::: "memory");
        } else if (t + 1 < KT) {
            asm volatile("s_waitcnt vmcnt(0)" ::: "memory");
        }
        __builtin_amdgcn_s_barrier();
        asm volatile("s_waitcnt lgkmcnt(0)" ::: "memory");
        mfma16<1>(a, b, acc);
        __builtin_amdgcn_s_barrier();
        rt = (rt == 4) ? 0 : rt + 1;
        rs = (rs == 4) ? 0 : rs + 1;
    }
}

// ---------------- kernel 1: cast x fp32 -> bf16 ----------------
__global__ __launch_bounds__(256) void cast_x_kernel(const float* __restrict__ x,
                                                     u16* __restrict__ xb) {
    size_t g = (size_t)blockIdx.x * 256 + threadIdx.x;
    f32x4 v = ((const f32x4*)x)[g];
    u16 o[4] = {f32_to_bf16(v.x), f32_to_bf16(v.y), f32_to_bf16(v.z), f32_to_bf16(v.w)};
    *(unsigned long long*)(xb + g * 4) = *(const unsigned long long*)o;
}

// ---------------- kernel 2: transpose-cast W [k][n] fp32 -> Wt [n][k] bf16 ----------------
__global__ __launch_bounds__(256) void transpose_w_kernel(const float* __restrict__ wq,
                                                          const float* __restrict__ wk,
                                                          const float* __restrict__ wv,
                                                          u16* __restrict__ wt) {
    __shared__ __align__(16) u16 tile[64][80];
    const float* w = blockIdx.z == 0 ? wq : (blockIdx.z == 1 ? wk : wv);
    int k0 = blockIdx.x * 64, n0 = blockIdx.y * 64;
    for (int g = threadIdx.x; g < 1024; g += 256) {
        int r = g >> 4, c = (g & 15) << 2;
        f32x4 v = *(const f32x4*)(w + (size_t)(k0 + r) * 1024 + n0 + c);
        tile[r][c + 0] = f32_to_bf16(v.x);
        tile[r][c + 1] = f32_to_bf16(v.y);
        tile[r][c + 2] = f32_to_bf16(v.z);
        tile[r][c + 3] = f32_to_bf16(v.w);
    }
    __syncthreads();
    u16* out = wt + (size_t)blockIdx.z * 1024 * 1024;
    for (int g = threadIdx.x; g < 512; g += 256) {
        int nr = g >> 3, kc = (g & 7) << 3;
        __align__(16) u16 tmp[8];
#pragma unroll
        for (int i = 0; i < 8; ++i) tmp[i] = tile[kc + i][nr];
        *(u32x4*)(out + (size_t)(n0 + nr) * 1024 + k0 + kc) = *(const u32x4*)tmp;
    }
}

// ---------------- kernel 3: QKV GEMM ----------------
// XCD-exclusive mt bands: xcd k owns mt k*8..k*8+7 (A panels never cross XCDs,
// 8 x 0.5 MB = 4 MB ~ one XCD L2); within an XCD, groups of 32 resident
// blocks cover 8mt x 4nt.
__global__ __launch_bounds__(512, 2) void gemm_qkv_kernel(const u16* __restrict__ xb,
                                                          const u16* __restrict__ wt,
                                                          u16* __restrict__ qkv) {
    __shared__ __align__(16) u16 lds[2 * NSLOT * U4];
    u16* ldsA = lds;
    u16* ldsB = lds + NSLOT * U4;
    int wg = blockIdx.x;
    int xcd = wg & 7;
    int r = wg >> 3;           // 0..95
    int ng = r >> 5;           // 0..2
    int j = r & 31;
    int mt = xcd * 8 + (j & 7);      // 0..63
    int nt = ng * 4 + (j >> 3);      // 0..11
    const u16* A = xb + (size_t)mt * 256 * 1024;
    const u16* B = wt + (size_t)nt * 256 * 1024;
    int tid = threadIdx.x;
    f32x4 acc[8][4] = {};
    gemm_block_256(A, 1024, B, 1024, 32, ldsA, ldsB, tid, acc);
    int lane = tid & 63, wv = tid >> 6;
    int wm = wv >> 2, wn = wv & 3;
    int r0 = (lane >> 4) << 2, c0 = lane & 15;
    size_t mbase = (size_t)mt * 256 + wm * 128;
    int nbase = nt * 256 + wn * 64;
#pragma unroll
    for (int i = 0; i < 8; ++i)
#pragma unroll
        for (int jj = 0; jj < 4; ++jj) {
            int col = nbase + jj * 16 + c0;
            float scale = (col < 1024) ? 0.03125f : 1.0f;  // fold 1/sqrt(1024) into Q
#pragma unroll
            for (int rr = 0; rr < 4; ++rr) {
                size_t row = mbase + i * 16 + r0 + rr;
                qkv[row * (size_t)N_QKV + col] = f32_to_bf16(acc[i][jj][rr] * scale);
            }
        }
}

// ---------------- kernel 4: transpose V -> Vt [b][d][m] ----------------
__global__ __launch_bounds__(256) void transpose_v_kernel(const u16* __restrict__ qkv,
                                                          u16* __restrict__ vt) {
    __shared__ __align__(16) u16 tile[64][80];
    int m0 = blockIdx.x * 64, d0 = blockIdx.y * 64, b = blockIdx.z;
    const u16* src = qkv + (size_t)b * SEQ * N_QKV + 2048;  // V columns
    for (int g = threadIdx.x; g < 512; g += 256) {
        int r = g >> 3, c = (g & 7) << 3;
        *(u32x4*)&tile[r][c] = *(const u32x4*)(src + (size_t)(m0 + r) * N_QKV + d0 + c);
    }
    __syncthreads();
    u16* dst = vt + (size_t)b * DIM * SEQ;
    for (int g = threadIdx.x; g < 512; g += 256) {
        int dr = g >> 3, mc = (g & 7) << 3;
        __align__(16) u16 tmp[8];
#pragma unroll
        for (int i = 0; i < 8; ++i) tmp[i] = tile[mc + i][dr];
        *(u32x4*)(dst + (size_t)(d0 + dr) * SEQ + m0 + mc) = *(const u32x4*)tmp;
    }
}

// ---------------- kernel 5: S = Q . K^T, triangular 256-tile grid ----------------
// 1D grid 288; batch = wg&7 -> each XCD works one batch (Q/K panels local).
__global__ __launch_bounds__(512, 2) void gemm_scores_kernel(const u16* __restrict__ qkv,
                                                             u16* __restrict__ S) {
    __shared__ __align__(16) u16 lds[2 * NSLOT * U4];
    u16* ldsA = lds;
    u16* ldsB = lds + NSLOT * U4;
    int wg = blockIdx.x;
    int b = wg & 7;
    int t = wg >> 3;           // 0..35
    int ntile = 0;
#pragma unroll
    for (int it = 1; it < 8; ++it)
        if ((it * (it + 1)) / 2 <= t) ntile = it;
    int mtile = t - (ntile * (ntile + 1)) / 2;
    const u16* A = qkv + (size_t)b * SEQ * N_QKV + (size_t)ntile * 256 * N_QKV;        // Q rows
    const u16* B = qkv + (size_t)b * SEQ * N_QKV + (size_t)mtile * 256 * N_QKV + 1024; // K rows
    int tid = threadIdx.x;
    f32x4 acc[8][4] = {};
    gemm_block_256(A, N_QKV, B, N_QKV, 32, ldsA, ldsB, tid, acc);
    u16* out = S + (size_t)b * SEQ * SEQ + (size_t)ntile * 256 * SEQ + (size_t)mtile * 256;
    int lane = tid & 63, wv = tid >> 6;
    int wm = wv >> 2, wn = wv & 3;
    int r0 = (lane >> 4) << 2, c0 = lane & 15;
#pragma unroll
    for (int i = 0; i < 8; ++i)
#pragma unroll
        for (int jj = 0; jj < 4; ++jj) {
            int col = wn * 64 + jj * 16 + c0;
#pragma unroll
            for (int rr = 0; rr < 4; ++rr) {
                int row = wm * 128 + i * 16 + r0 + rr;
                out[(size_t)row * SEQ + col] = f32_to_bf16(acc[i][jj][rr]);
            }
        }
}

// ---------------- kernel 6: row softmax over bf16 S, in-place ----------------
__global__ __launch_bounds__(256) void softmax_kernel(u16* __restrict__ SP) {
    int gr = blockIdx.x;
    int n = gr & 2047;
    u16* s = SP + (size_t)gr * SEQ;
    __shared__ float red[4];
    int t = threadIdx.x;
    int base = t << 3;
    int len = n + 1;
    float v[8];
    float lmax = -3.0e38f;
    if (base < len) {
        u32x4 raw = *(const u32x4*)(s + base);
        const u16* h = (const u16*)&raw;
#pragma unroll
        for (int i = 0; i < 8; ++i) {
            v[i] = (base + i < len) ? bf16_to_f32(h[i]) : -3.0e38f;
            lmax = fmaxf(lmax, v[i]);
        }
    } else {
#pragma unroll
        for (int i = 0; i < 8; ++i) v[i] = -3.0e38f;
    }
#pragma unroll
    for (int off = 32; off; off >>= 1) lmax = fmaxf(lmax, __shfl_xor(lmax, off, 64));
    if ((t & 63) == 0) red[t >> 6] = lmax;
    __syncthreads();
    float gmax = fmaxf(fmaxf(red[0], red[1]), fmaxf(red[2], red[3]));
    __syncthreads();
    float lsum = 0.f;
#pragma unroll
    for (int i = 0; i < 8; ++i) {
        float e = __expf(v[i] - gmax);
        v[i] = e;
        lsum += e;
    }
#pragma unroll
    for (int off = 32; off; off >>= 1) lsum += __shfl_xor(lsum, off, 64);
    if ((t & 63) == 0) red[t >> 6] = lsum;
    __syncthreads();
    float inv = 1.0f / (red[0] + red[1] + red[2] + red[3]);
    __align__(16) u16 o[8];
#pragma unroll
    for (int i = 0; i < 8; ++i) o[i] = f32_to_bf16(v[i] * inv);
    *(u32x4*)(s + base) = *(const u32x4*)o;
}

// ---------------- kernel 7: O = P . V (via Vt), causal K truncation ----------------
// 1D grid 256 (all resident); batch = wg&7 -> per-XCD batch locality.
__global__ __launch_bounds__(512, 2) void gemm_out_kernel(const u16* __restrict__ P,
                                                          const u16* __restrict__ vt,
                                                          float* __restrict__ O) {
    __shared__ __align__(16) u16 lds[2 * NSLOT * U4];
    u16* ldsA = lds;
    u16* ldsB = lds + NSLOT * U4;
    int wg = blockIdx.x;
    int b = wg & 7;
    int r = wg >> 3;           // 0..31
    int dt = r & 3;
    int ntile = r >> 2;        // 0..7
    const u16* A = P + (size_t)b * SEQ * SEQ + (size_t)ntile * 256 * SEQ;
    const u16* B = vt + (size_t)b * DIM * SEQ + (size_t)dt * 256 * SEQ;
    int tid = threadIdx.x;
    f32x4 acc[8][4] = {};
    int KT = (ntile + 1) * 8;  // keys beyond (ntile+1)*256 have P == 0 (BK=32 units)
    gemm_block_256(A, SEQ, B, SEQ, KT, ldsA, ldsB, tid, acc);
    float* out = O + (size_t)b * SEQ * DIM + (size_t)ntile * 256 * DIM + (size_t)dt * 256;
    int lane = tid & 63, wv = tid >> 6;
    int wm = wv >> 2, wn = wv & 3;
    int r0 = (lane >> 4) << 2, c0 = lane & 15;
#pragma unroll
    for (int i = 0; i < 8; ++i)
#pragma unroll
        for (int jj = 0; jj < 4; ++jj) {
            int col = wn * 64 + jj * 16 + c0;
#pragma unroll
            for (int rr = 0; rr < 4; ++rr) {
                int row = wm * 128 + i * 16 + r0 + rr;
                out[(size_t)row * DIM + col] = acc[i][jj][rr];
            }
        }
}

extern "C" void kernel_launch(void* const* d_in, const int* in_sizes, int n_in,
                              void* d_out, int out_size, void* d_ws, size_t ws_size,
                              hipStream_t stream) {
    const float* x = (const float*)d_in[0];
    const float* wq = (const float*)d_in[1];
    const float* wk = (const float*)d_in[2];
    const float* wv = (const float*)d_in[3];
    char* ws = (char*)d_ws;
    u16* qkv = (u16*)(ws + OFF_QKV);
    u16* vt = (u16*)(ws + OFF_VT);
    u16* xb = (u16*)(ws + OFF_XB);
    u16* wt = (u16*)(ws + OFF_WT);
    u16* S = (u16*)(ws + OFF_S);   // aliases xb/wt region (dead by then)
    float* O = (float*)d_out;

    cast_x_kernel<<<M_TOT * DIM / 4 / 256, 256, 0, stream>>>(x, xb);
    transpose_w_kernel<<<dim3(16, 16, 3), 256, 0, stream>>>(wq, wk, wv, wt);
    gemm_qkv_kernel<<<(M_TOT / 256) * (N_QKV / 256), 512, 0, stream>>>(xb, wt, qkv);
    transpose_v_kernel<<<dim3(SEQ / 64, DIM / 64, BATCH), 256, 0, stream>>>(qkv, vt);
    gemm_scores_kernel<<<36 * BATCH, 512, 0, stream>>>(qkv, S);
    softmax_kernel<<<BATCH * SEQ, 256, 0, stream>>>(S);
    gemm_out_kernel<<<(DIM / 256) * (SEQ / 256) * BATCH, 512, 0, stream>>>(S, vt, O);
}